// Round 2
// baseline (971.579 us; speedup 1.0000x reference)
//
#include <hip/hip_runtime.h>

#define NT 2000
#define NS 2048
#define NH 16
#define U 16
#define NG (NT / U)   // 125 groups, exact

// v + (v shifted right by N lanes within the 16-lane DPP row, 0-filled).
// row_shr:N ctrl = 0x110|N. old=0 + bound_ctrl=false -> shifted-out lanes read 0.
#define DPP_SHR_ADD(v, ctrl) \
    ((v) + __int_as_float(__builtin_amdgcn_update_dpp( \
        0, __float_as_int(v), (ctrl), 0xf, 0xf, false)))

// 3-stage producer-consumer pipeline: wave0 = SnowBucket (f chain),
// wave1 = SoilBucket (h chain), wave2 = LinearBucket (g chain) + Q reduce.
// Each block owns 4 sites x 16 heads (lane = s*16+nh within the 64-lane wave,
// nh fastest so Fh/Hh/Gh stores are coalesced 256B). Hand-off via
// double-buffered LDS, one s_barrier per 16-step group; wave1 lags wave0 by
// one group, wave2 by two. This triples waves/CU (2 -> 6) and splits the
// ~12-deep per-timestep dependency chain into three short chains that overlap.
// All waves execute exactly NG+2 barriers (divergent-barrier producer/consumer
// pattern; barrier counts match).
__global__ __launch_bounds__(192) void waternet_kernel(
    const float* __restrict__ P, const float* __restrict__ T,
    const float* __restrict__ E,
    const float* __restrict__ w_o, const float* __restrict__ wF,
    const float* __restrict__ wG, const float* __restrict__ wl,
    const float* __restrict__ we, const float* __restrict__ wk,
    const float* __restrict__ ws,
    float* __restrict__ Q, float* __restrict__ Fh,
    float* __restrict__ Hh, float* __restrict__ Gh)
{
    __shared__ float Xs [2][U][64];   // wave0 -> wave1 : x
    __shared__ float QBs[2][U][64];   // wave1 -> wave2 : q2b
    __shared__ float QAs[2][U][64];   // wave1 -> wave2 : q1 + q2a

    const int lane = threadIdx.x & 63;
    const int wave = threadIdx.x >> 6;
    const int c    = blockIdx.x * 64 + lane;   // chain id
    const int s    = c >> 4;
    const int nh   = c & 15;
    const size_t ostride = (size_t)NS * NH;

    if (wave == 0) {
        // ---------------- SnowBucket: f chain ----------------
        const float melt = expf(wF[nh]) + 1.0f;
        float f = 0.0f;
        float* pf = Fh + (size_t)s * NH + nh;
        int li = s;
        float Pb[U], Tb[U];
        #pragma unroll
        for (int j = 0; j < U; ++j) { Pb[j] = P[li]; Tb[j] = T[li]; li += NS; }

        for (int it = 0; it < NG + 2; ++it) {
            if (it < NG) {
                float Pc[U], Tc[U];
                #pragma unroll
                for (int j = 0; j < U; ++j) { Pc[j] = Pb[j]; Tc[j] = Tb[j]; }
                if (it + 1 < NG) {
                    #pragma unroll
                    for (int j = 0; j < U; ++j) { Pb[j] = P[li]; Tb[j] = T[li]; li += NS; }
                }
                float* xrow = &Xs[it & 1][0][lane];
                #pragma unroll
                for (int j = 0; j < U; ++j) {
                    const float Tk = Tc[j], Pk = Pc[j];
                    const float sm = fmaxf(Tk, 0.0f) * melt;
                    const float m  = fminf(sm, f);
                    f = f - m + (Tk < 0.0f ? Pk : 0.0f);
                    const float x  = (Tk > 0.0f ? Pk : 0.0f) + m;
                    *pf = f; pf += ostride;
                    xrow[j * 64] = x;
                }
            }
            __syncthreads();
        }
    } else if (wave == 1) {
        // ---------------- SoilBucket: h chain ----------------
        const float cap = expf(2.0f * wl[nh]);
        const float swe = 1.0f / (1.0f + expf(-we[nh]));
        const float swk = 1.0f / (1.0f + expf(-wk[nh]));
        const float sws = 1.0f / (1.0f + expf(-ws[nh]));
        const float omsws = 1.0f - sws;
        float h = 0.0f;
        float* ph = Hh + (size_t)s * NH + nh;
        int li = s;
        float Eb[U];
        #pragma unroll
        for (int j = 0; j < U; ++j) { Eb[j] = E[li]; li += NS; }

        for (int it = 0; it < NG + 2; ++it) {
            const int k = it - 1;
            if (k >= 0 && k < NG) {
                float Ec[U];
                #pragma unroll
                for (int j = 0; j < U; ++j) Ec[j] = Eb[j];
                if (k + 1 < NG) {
                    #pragma unroll
                    for (int j = 0; j < U; ++j) { Eb[j] = E[li]; li += NS; }
                }
                float Xc[U];
                #pragma unroll
                for (int j = 0; j < U; ++j) Xc[j] = Xs[k & 1][j][lane];
                float* qbrow = &QBs[k & 1][0][lane];
                float* qarow = &QAs[k & 1][0][lane];
                #pragma unroll
                for (int j = 0; j < U; ++j) {
                    const float hn = h + Xc[j];
                    const float h1 = fmaxf(hn - cap, 0.0f);
                    const float q1 = fmaxf(h1 - Ec[j] * swe, 0.0f);
                    const float h2 = hn - h1;
                    const float q2 = h2 * swk;
                    h = h2 - q2;
                    *ph = h; ph += ostride;
                    qbrow[j * 64] = q2 * omsws;
                    qarow[j * 64] = q1 + q2 * sws;
                }
            }
            __syncthreads();
        }
    } else {
        // ---------- LinearBucket: g chain + Q head-reduce ----------
        float mx = -INFINITY;
        #pragma unroll
        for (int i = 0; i < NH; ++i) mx = fmaxf(mx, w_o[i]);
        float ssum = 0.f;
        #pragma unroll
        for (int i = 0; i < NH; ++i) ssum += expf(w_o[i] - mx);
        const float a   = expf(w_o[nh] - mx) / ssum;
        const float swG = 1.0f / (1.0f + expf(-wG[nh]));
        float g = 0.0f;
        float* pg = Gh + (size_t)s * NH + nh;
        float* pq = Q + s;

        for (int it = 0; it < NG + 2; ++it) {
            const int k = it - 2;
            if (k >= 0) {
                float qb[U], qa[U];
                #pragma unroll
                for (int j = 0; j < U; ++j) {
                    qb[j] = QBs[k & 1][j][lane];
                    qa[j] = QAs[k & 1][j][lane];
                }
                float qs[U];
                #pragma unroll
                for (int j = 0; j < U; ++j) {
                    const float q3 = (qb[j] + g) * swG;
                    g = g - q3 + qb[j];
                    *pg = g; pg += ostride;
                    qs[j] = (qa[j] + q3) * a;
                }
                // 16-lane row sums via DPP prefix adds: lane nh==15 gets total.
                #pragma unroll
                for (int j = 0; j < U; ++j) {
                    float v = qs[j];
                    v = DPP_SHR_ADD(v, 0x111);   // row_shr:1
                    v = DPP_SHR_ADD(v, 0x112);   // row_shr:2
                    v = DPP_SHR_ADD(v, 0x114);   // row_shr:4
                    v = DPP_SHR_ADD(v, 0x118);   // row_shr:8
                    qs[j] = v;
                }
                if (nh == 15) {
                    #pragma unroll
                    for (int j = 0; j < U; ++j)
                        pq[(size_t)(k * U + j) * NS] = qs[j];
                }
            }
            __syncthreads();
        }
    }
}

extern "C" void kernel_launch(void* const* d_in, const int* in_sizes, int n_in,
                              void* d_out, int out_size, void* d_ws, size_t ws_size,
                              hipStream_t stream) {
    const float* P   = (const float*)d_in[0];
    const float* T   = (const float*)d_in[1];
    const float* E   = (const float*)d_in[2];
    const float* w_o = (const float*)d_in[3];
    const float* wF  = (const float*)d_in[4];
    const float* wG  = (const float*)d_in[5];
    const float* wl  = (const float*)d_in[6];
    const float* we  = (const float*)d_in[7];
    const float* wk  = (const float*)d_in[8];
    const float* ws  = (const float*)d_in[9];

    float* Q  = (float*)d_out;
    float* Fh = Q  + (size_t)NT * NS;
    float* Hh = Fh + (size_t)NT * NS * NH;
    float* Gh = Hh + (size_t)NT * NS * NH;

    dim3 block(192);                       // 3 waves: snow / soil / linear
    dim3 grid(NS * NH / 64);               // 512 blocks -> 6 waves/CU
    waternet_kernel<<<grid, block, 0, stream>>>(P, T, E, w_o, wF, wG, wl, we, wk, ws,
                                                Q, Fh, Hh, Gh);
}